// Round 23
// baseline (140.730 us; speedup 1.0000x reference)
//
#include <hip/hip_runtime.h>
#include <cstddef>

#define T_STEPS 256
#define OBS     32
#define ACTD    8
#define NB      16      // sequences per block (full N-dim of transposed MFMA)
#define HPAD2   152     // Bop row stride in f16 (304 B)
#define NSEQ    4096

typedef _Float16 f16x8 __attribute__((ext_vector_type(8)));
typedef _Float16 f16x4 __attribute__((ext_vector_type(4)));
typedef _Float16 f16x2 __attribute__((ext_vector_type(2)));
typedef float    f32x4 __attribute__((ext_vector_type(4)));

union F8 { f16x8 v; _Float16 e[8]; f16x2 h2[4]; };
union F4 { f16x4 v; _Float16 e[4]; f16x2 h2[2]; };

#define LOG2E 1.44269504088896f

__device__ __forceinline__ f16x2 pkrtz(float a, float b) {
    return __builtin_bit_cast(f16x2, __builtin_amdgcn_cvt_pkrtz(a, b));
}

__global__ __launch_bounds__(512)
void lstm_fused(const float* __restrict__ obss, const float* __restrict__ actions,
                const float* __restrict__ W, const float* __restrict__ b,
                const float* __restrict__ Wdec, const float* __restrict__ bdec_p,
                float* __restrict__ out)
{
    // R17 structure (best: 133.8us), with B-staging deduplicated to wave B0 only.
    // Unified B-operand Bop: cols 0..63 phi(h) (A writes), 64..103 pi(x) (B0
    // writes f16 frags 1 step ahead), col 100 = 1.0 bias (written once).
    // A-waves (0-3): all 16 MFMAs + cell update + h write.
    // B-wave 4 (w=0): x loads/cvt/stage. B-waves 4-7: rotating output duty.
    __shared__ __align__(16) _Float16 Bop[2][NB * HPAD2];
    __shared__ __align__(16) float partb[2][16][20];   // [buf][seq][16 partials]

    const int tid  = threadIdx.x;
    const int w8   = tid >> 6;            // physical wave 0..7
    const int w    = w8 & 3;              // unit-slice 0..3
    const bool isA = w8 < 4;
    const int wS   = __builtin_amdgcn_readfirstlane(w);
    const int lane = tid & 63;
    const int g    = lane >> 4;           // k-group / D-row-group
    const int m    = lane & 15;           // seq (B col / D col)
    const int n0   = blockIdx.x * NB;
    const int u0   = 16 * w + 4 * g;      // first of 4 units an A-lane updates
    const int sigb = 32 * (w >> 1) + 8 * g + 4 * (w & 1);  // = phi(u0), 8B-aligned

    // ---- A-waves: all W fragments (4 gates x 4 K-tiles) ----
    f16x8 AW[4][4];
    f32x4 wdv = {0.f, 0.f, 0.f, 0.f};
    if (isA) {
        const float* Wc = W + 16 * w + m;     // tile e -> gate-col 64e + 16w + m
#pragma unroll
        for (int e = 0; e < 4; e++) {
#pragma unroll
            for (int c = 0; c < 2; c++) {     // h tiles: k 0..63 -> W row 40+k
                F8 hi;
#pragma unroll
                for (int i = 0; i < 8; i++) {
                    int k = 32 * c + 16 * (i >> 2) + 4 * g + (i & 3);
                    hi.e[i] = (_Float16)Wc[(40 + k) * 256 + 64 * e];
                }
                AW[e][c] = hi.v;
            }
            F8 xo, xA;
            float bv = b[64 * e + 16 * w + m] + (e == 2 ? 1.0f : 0.0f);
#pragma unroll
            for (int i = 0; i < 8; i++) {
                int kk = 16 * (i >> 2) + 4 * g + (i & 3);              // 0..31
                xo.e[i] = (_Float16)Wc[kk * 256 + 64 * e];             // obs dims
                xA.e[i] = (kk < ACTD) ? (_Float16)Wc[(OBS + kk) * 256 + 64 * e]
                        : (kk == 16)  ? (_Float16)bv                   // bias slot
                                      : (_Float16)0.0f;
            }
            AW[e][2] = xo.v;
            AW[e][3] = xA.v;
        }
        wdv = *(const f32x4*)&Wdec[u0];
    }
    const float bd = bdec_p[0];

    for (int i = tid; i < 2 * NB * HPAD2; i += 512)
        (&Bop[0][0])[i] = (_Float16)0.0f;
    __syncthreads();
    if (tid < 32)                          // bias B-val 1.0 at col 100, both buffers
        Bop[tid >> 4][(tid & 15) * HPAD2 + 100] = (_Float16)1.0f;

    // ---- B0-wave x pipeline (dedup: only w8==4 stages) ----
    const float* pO = obss    + ((size_t)(n0 + m) * T_STEPS) * OBS  + 4 * g;
    const float* pA = actions + ((size_t)(n0 + m) * T_STEPS) * ACTD + 4 * g;
    f32x4 xo0 = {0,0,0,0}, xo1 = {0,0,0,0}, xa = {0,0,0,0};
    auto loadx = [&]() {
        xo0 = *(const f32x4*)pO;
        xo1 = *(const f32x4*)(pO + 16);
        pO += OBS;
        if (g < 2) { xa = *(const f32x4*)pA; pA += ACTD; }
    };
    f16x8 bxo;
    f16x4 uaq;
    auto cvtx = [&]() {
        F8 uo;
        uo.h2[0] = pkrtz(xo0[0], xo0[1]);
        uo.h2[1] = pkrtz(xo0[2], xo0[3]);
        uo.h2[2] = pkrtz(xo1[0], xo1[1]);
        uo.h2[3] = pkrtz(xo1[2], xo1[3]);
        F4 ua_;
        ua_.h2[0] = pkrtz(xa[0], xa[1]);
        ua_.h2[1] = pkrtz(xa[2], xa[3]);
        bxo = uo.v;
        uaq = ua_.v;
    };
    auto stagex = [&](int buf) {           // pi-permuted: frags land verbatim
        _Float16* xp = &Bop[buf][m * HPAD2 + 64];
        *(f16x8*)(xp + 8 * g) = bxo;                   // obs -> cols 64+8g..+7
        if (g < 2) *(f16x4*)(xp + 32 + 8 * g) = uaq;   // act -> cols 96+8g..+3
    };
    const bool isB0 = (!isA) && (wS == 0);

    if (isB0) {
        loadx();          // x_0
        cvtx();
        stagex(0);        // x_0 into buffer 0
        loadx();          // x_1 (cvt'd + staged at t=0 tail)
    }
    f32x4 cr = {0.f, 0.f, 0.f, 0.f};      // A: c state, units u0..u0+3 of seq m
    float* pOut = out + (size_t)((w + 3) & 3) * NSEQ + n0 + lane;

    __syncthreads();

#pragma unroll 2
    for (int t = 0; t < T_STEPS; ++t) {
        const int cb  = t & 1;
        const int nb2 = cb ^ 1;
        // LDS-only barrier: B0's global x loads may span it
        asm volatile("s_waitcnt lgkmcnt(0)\n\ts_barrier" ::: "memory");

        if (isA) {
            // one fragment set, shared by all 4 gate tiles
            const _Float16* bp = &Bop[cb][m * HPAD2];
            f16x8 f0 = *(const f16x8*)(bp + 8 * g);           // h k 0..31
            f16x8 f1 = *(const f16x8*)(bp + 32 + 8 * g);      // h k 32..63
            f16x8 f2 = *(const f16x8*)(bp + 64 + 8 * g);      // x obs
            f16x8 f3 = *(const f16x8*)(bp + 96 + 8 * g);      // x act + bias

            f32x4 acc[4];
            __builtin_amdgcn_s_setprio(1);
#pragma unroll
            for (int e = 0; e < 4; e++) {
                const f32x4 z = {0.f, 0.f, 0.f, 0.f};
                f32x4 aA = __builtin_amdgcn_mfma_f32_16x16x32_f16(AW[e][2], f2, z, 0, 0, 0);
                f32x4 aB = __builtin_amdgcn_mfma_f32_16x16x32_f16(AW[e][3], f3, z, 0, 0, 0);
                aA = __builtin_amdgcn_mfma_f32_16x16x32_f16(AW[e][0], f0, aA, 0, 0, 0);
                aB = __builtin_amdgcn_mfma_f32_16x16x32_f16(AW[e][1], f1, aB, 0, 0, 0);
                acc[e] = aA + aB;
            }
            __builtin_amdgcn_s_setprio(0);

            // cell update, fused single-rcp (R17 formulas verbatim)
            float h4[4];
#pragma unroll
            for (int r = 0; r < 4; r++) {
                float ef = __builtin_amdgcn_exp2f(acc[2][r] * -LOG2E);
                float ei = __builtin_amdgcn_exp2f(acc[0][r] * -LOG2E);
                float ej = __builtin_amdgcn_exp2f(acc[1][r] * (-2.0f * LOG2E));
                float Fv = 1.0f + ef, Av = 1.0f + ei, Bv = 1.0f + ej;
                float AB = Av * Bv;
                float num = fmaf(cr[r], AB, Fv * (Bv - 2.0f));
                float c = num * __builtin_amdgcn_rcpf(Fv * AB);
                cr[r] = c;
                float ec = __builtin_amdgcn_exp2f(c * (-2.0f * LOG2E));
                float eo = __builtin_amdgcn_exp2f(acc[3][r] * -LOG2E);
                float Dv = 1.0f + ec, Ev = 1.0f + eo;
                h4[r] = (Dv - 2.0f) * __builtin_amdgcn_rcpf(Dv * Ev);
            }
            // pack and write h as one b64 (phi layout)
            F4 hi_;
            hi_.h2[0] = pkrtz(h4[0], h4[1]);
            hi_.h2[1] = pkrtz(h4[2], h4[3]);
            *(f16x4*)(&Bop[nb2][m * HPAD2 + sigb]) = hi_.v;

            // decode partial: per-lane 4-FMA, direct LDS slot
            float p = h4[0] * wdv[0];
            p = fmaf(h4[1], wdv[1], p);
            p = fmaf(h4[2], wdv[2], p);
            p = fmaf(h4[3], wdv[3], p);
            partb[cb][m][4 * w + g] = p;
        } else {
            // producer (B0 only): convert + stage x_{t+1}; issue x_{t+2} loads
            if (isB0) {
                if (t + 1 < T_STEPS) {
                    cvtx();
                    stagex(nb2);
                }
                if (t + 2 < T_STEPS) loadx();
            }
            // output duty (rotates over all B-waves): reduce prev step's partials
            if (t > 0 && wS == (t & 3) && lane < 16) {
                const float* pp = &partb[nb2][lane][0];
                f32x4 q0 = *(const f32x4*)pp;
                f32x4 q1 = *(const f32x4*)(pp + 4);
                f32x4 q2 = *(const f32x4*)(pp + 8);
                f32x4 q3 = *(const f32x4*)(pp + 12);
                f32x4 s4 = (q0 + q1) + (q2 + q3);
                *pOut = s4[0] + s4[1] + s4[2] + s4[3] + bd;
                pOut += 4 * NSEQ;
            }
        }
    }

    // final row (t = T_STEPS-1 partials live in partb[1]); B-wave 0 serves it
    __syncthreads();
    if (!isA && wS == 0 && lane < 16) {
        const float* pp = &partb[1][lane][0];
        f32x4 q0 = *(const f32x4*)pp;
        f32x4 q1 = *(const f32x4*)(pp + 4);
        f32x4 q2 = *(const f32x4*)(pp + 8);
        f32x4 q3 = *(const f32x4*)(pp + 12);
        f32x4 s4 = (q0 + q1) + (q2 + q3);
        *pOut = s4[0] + s4[1] + s4[2] + s4[3] + bd;
    }
}

extern "C" void kernel_launch(void* const* d_in, const int* in_sizes, int n_in,
                              void* d_out, int out_size, void* d_ws, size_t ws_size,
                              hipStream_t stream) {
    (void)in_sizes; (void)n_in; (void)d_ws; (void)ws_size; (void)out_size;
    const float* obss    = (const float*)d_in[0];
    const float* actions = (const float*)d_in[1];
    const float* W       = (const float*)d_in[2];
    const float* b       = (const float*)d_in[3];
    const float* Wdec    = (const float*)d_in[4];
    const float* bdec    = (const float*)d_in[5];
    float* out = (float*)d_out;
    lstm_fused<<<dim3(NSEQ / NB), dim3(512), 0, stream>>>(obss, actions, W, b, Wdec, bdec, out);
}

// Round 24
// 133.774 us; speedup vs baseline: 1.0520x; 1.0520x over previous
//
#include <hip/hip_runtime.h>
#include <cstddef>

#define T_STEPS 256
#define OBS     32
#define ACTD    8
#define NB      16      // sequences per block (full N-dim of transposed MFMA)
#define HPAD2   152     // Bop row stride in f16 (304 B; 76 dw == 12 mod 32)
#define NSEQ    4096

typedef _Float16 f16x8 __attribute__((ext_vector_type(8)));
typedef _Float16 f16x4 __attribute__((ext_vector_type(4)));
typedef _Float16 f16x2 __attribute__((ext_vector_type(2)));
typedef float    f32x4 __attribute__((ext_vector_type(4)));

union F8 { f16x8 v; _Float16 e[8]; f16x2 h2[4]; };
union F4 { f16x4 v; _Float16 e[4]; f16x2 h2[2]; };

#define LOG2E 1.44269504088896f

__device__ __forceinline__ f16x2 pkrtz(float a, float b) {
    return __builtin_bit_cast(f16x2, __builtin_amdgcn_cvt_pkrtz(a, b));
}

__global__ __launch_bounds__(512)
void lstm_fused(const float* __restrict__ obss, const float* __restrict__ actions,
                const float* __restrict__ W, const float* __restrict__ b,
                const float* __restrict__ Wdec, const float* __restrict__ bdec_p,
                float* __restrict__ out)
{
    // Unified B-operand LDS: per seq row, cols 0..63 = phi(h) (A writes),
    // cols 64..103 = pi-permuted x (B writes f16 frags), col 100 = 1.0 (bias slot,
    // written once), rest zero pad. K = 4 tiles of 32.
    // A-waves (0-3): all 16 MFMAs (4 tiles x 4 gates) + cell update + h write.
    // B-waves (4-7): x loads/cvt -> 3 small LDS stores (1 step ahead) + output duty.
    __shared__ __align__(16) _Float16 Bop[2][NB * HPAD2];
    __shared__ __align__(16) float partb[2][16][20];   // [buf][seq][16 partials]

    const int tid  = threadIdx.x;
    const int w8   = tid >> 6;            // physical wave 0..7
    const int w    = w8 & 3;              // unit-slice 0..3
    const bool isA = w8 < 4;
    const int lane = tid & 63;
    const int g    = lane >> 4;           // k-group / D-row-group
    const int m    = lane & 15;           // seq (B col / D col)
    const int n0   = blockIdx.x * NB;
    const int u0   = 16 * w + 4 * g;      // first of 4 units an A-lane updates
    const int sigb = 32 * (w >> 1) + 8 * g + 4 * (w & 1);  // = phi(u0), 8B-aligned

    // ---- A-waves: all W fragments (4 gates x 4 K-tiles) ----
    f16x8 AW[4][4];
    f32x4 wdv = {0.f, 0.f, 0.f, 0.f};
    if (isA) {
        const float* Wc = W + 16 * w + m;     // tile e -> gate-col 64e + 16w + m
#pragma unroll
        for (int e = 0; e < 4; e++) {
#pragma unroll
            for (int c = 0; c < 2; c++) {     // h tiles: k 0..63 -> W row 40+k
                F8 hi;
#pragma unroll
                for (int i = 0; i < 8; i++) {
                    int k = 32 * c + 16 * (i >> 2) + 4 * g + (i & 3);
                    hi.e[i] = (_Float16)Wc[(40 + k) * 256 + 64 * e];
                }
                AW[e][c] = hi.v;
            }
            F8 xo, xA;
            float bv = b[64 * e + 16 * w + m] + (e == 2 ? 1.0f : 0.0f);
#pragma unroll
            for (int i = 0; i < 8; i++) {
                int kk = 16 * (i >> 2) + 4 * g + (i & 3);              // 0..31
                xo.e[i] = (_Float16)Wc[kk * 256 + 64 * e];             // obs dims
                xA.e[i] = (kk < ACTD) ? (_Float16)Wc[(OBS + kk) * 256 + 64 * e]
                        : (kk == 16)  ? (_Float16)bv                   // bias slot
                                      : (_Float16)0.0f;
            }
            AW[e][2] = xo.v;
            AW[e][3] = xA.v;
        }
        wdv = *(const f32x4*)&Wdec[u0];
    }
    const float bd = bdec_p[0];

    for (int i = tid; i < 2 * NB * HPAD2; i += 512)
        (&Bop[0][0])[i] = (_Float16)0.0f;
    __syncthreads();
    if (tid < 32)                          // bias B-val 1.0 at col 100, both buffers
        Bop[tid >> 4][(tid & 15) * HPAD2 + 100] = (_Float16)1.0f;

    // ---- B-wave x pipeline ----
    const float* pO = obss    + ((size_t)(n0 + m) * T_STEPS) * OBS  + 4 * g;
    const float* pA = actions + ((size_t)(n0 + m) * T_STEPS) * ACTD + 4 * g;
    f32x4 xo0 = {0,0,0,0}, xo1 = {0,0,0,0}, xa = {0,0,0,0};
    auto loadx = [&]() {
        xo0 = *(const f32x4*)pO;
        xo1 = *(const f32x4*)(pO + 16);
        pO += OBS;
        if (g < 2) { xa = *(const f32x4*)pA; pA += ACTD; }
    };
    f16x8 bxo;
    f16x4 uaq;
    auto cvtx = [&]() {
        F8 uo;
        uo.h2[0] = pkrtz(xo0[0], xo0[1]);
        uo.h2[1] = pkrtz(xo0[2], xo0[3]);
        uo.h2[2] = pkrtz(xo1[0], xo1[1]);
        uo.h2[3] = pkrtz(xo1[2], xo1[3]);
        F4 ua_;
        ua_.h2[0] = pkrtz(xa[0], xa[1]);
        ua_.h2[1] = pkrtz(xa[2], xa[3]);
        bxo = uo.v;
        uaq = ua_.v;
    };
    auto stagex = [&](int buf) {           // pi-permuted: frags land verbatim
        _Float16* xp = &Bop[buf][m * HPAD2 + 64];
        *(f16x8*)(xp + 8 * g) = bxo;                   // obs -> cols 64+8g..+7
        if (g < 2) *(f16x4*)(xp + 32 + 8 * g) = uaq;   // act -> cols 96+8g..+3
    };

    if (!isA) {
        loadx();          // x_0
        cvtx();
        stagex(0);        // x_0 into buffer 0
        loadx();          // x_1 (cvt'd + staged at t=0)
    }
    f32x4 cr = {0.f, 0.f, 0.f, 0.f};      // A: c state, units u0..u0+3 of seq m
    float* pOut = out + (size_t)((w + 3) & 3) * NSEQ + n0 + lane;

    __syncthreads();

#pragma unroll 2
    for (int t = 0; t < T_STEPS; ++t) {
        const int cb  = t & 1;
        const int nb2 = cb ^ 1;
        // LDS-only barrier: B's global x loads may span it
        asm volatile("s_waitcnt lgkmcnt(0)\n\ts_barrier" ::: "memory");

        if (isA) {
            // one fragment set, shared by all 4 gate tiles
            const _Float16* bp = &Bop[cb][m * HPAD2];
            f16x8 f0 = *(const f16x8*)(bp + 8 * g);           // h k 0..31
            f16x8 f1 = *(const f16x8*)(bp + 32 + 8 * g);      // h k 32..63
            f16x8 f2 = *(const f16x8*)(bp + 64 + 8 * g);      // x obs
            f16x8 f3 = *(const f16x8*)(bp + 96 + 8 * g);      // x act + bias

            f32x4 acc[4];
#pragma unroll
            for (int e = 0; e < 4; e++) {
                const f32x4 z = {0.f, 0.f, 0.f, 0.f};
                f32x4 aA = __builtin_amdgcn_mfma_f32_16x16x32_f16(AW[e][2], f2, z, 0, 0, 0);
                f32x4 aB = __builtin_amdgcn_mfma_f32_16x16x32_f16(AW[e][3], f3, z, 0, 0, 0);
                aA = __builtin_amdgcn_mfma_f32_16x16x32_f16(AW[e][0], f0, aA, 0, 0, 0);
                aB = __builtin_amdgcn_mfma_f32_16x16x32_f16(AW[e][1], f1, aB, 0, 0, 0);
                acc[e] = aA + aB;
            }

            // cell update, fused single-rcp c
            float h4[4];
#pragma unroll
            for (int r = 0; r < 4; r++) {
                float ef = __builtin_amdgcn_exp2f(acc[2][r] * -LOG2E);
                float ei = __builtin_amdgcn_exp2f(acc[0][r] * -LOG2E);
                float ej = __builtin_amdgcn_exp2f(acc[1][r] * (-2.0f * LOG2E));
                float Fv = 1.0f + ef, Av = 1.0f + ei, Bv = 1.0f + ej;
                float AB = Av * Bv;
                float num = fmaf(cr[r], AB, Fv * (Bv - 2.0f));
                float c = num * __builtin_amdgcn_rcpf(Fv * AB);
                cr[r] = c;
                float ec = __builtin_amdgcn_exp2f(c * (-2.0f * LOG2E));
                float eo = __builtin_amdgcn_exp2f(acc[3][r] * -LOG2E);
                float Dv = 1.0f + ec, Ev = 1.0f + eo;
                h4[r] = (Dv - 2.0f) * __builtin_amdgcn_rcpf(Dv * Ev);
            }
            // pack and write h as one b64 (phi layout)
            F4 hi_;
            hi_.h2[0] = pkrtz(h4[0], h4[1]);
            hi_.h2[1] = pkrtz(h4[2], h4[3]);
            *(f16x4*)(&Bop[nb2][m * HPAD2 + sigb]) = hi_.v;

            // decode partial: per-lane 4-FMA, direct LDS slot
            float p = h4[0] * wdv[0];
            p = fmaf(h4[1], wdv[1], p);
            p = fmaf(h4[2], wdv[2], p);
            p = fmaf(h4[3], wdv[3], p);
            partb[cb][m][4 * w + g] = p;
        } else {
            // producer: convert + stage x_{t+1}; issue x_{t+2} loads
            if (t + 1 < T_STEPS) {
                cvtx();
                stagex(nb2);
            }
            if (t + 2 < T_STEPS) loadx();

            // output duty (rotates): reduce prev step's 16 partials, store row t-1
            if (t > 0 && w == (t & 3) && lane < 16) {
                const float* pp = &partb[nb2][lane][0];
                f32x4 q0 = *(const f32x4*)pp;
                f32x4 q1 = *(const f32x4*)(pp + 4);
                f32x4 q2 = *(const f32x4*)(pp + 8);
                f32x4 q3 = *(const f32x4*)(pp + 12);
                f32x4 s4 = (q0 + q1) + (q2 + q3);
                *pOut = s4[0] + s4[1] + s4[2] + s4[3] + bd;
                pOut += 4 * NSEQ;
            }
        }
    }

    // final row (t = T_STEPS-1 partials live in partb[1]); B-wave 0 serves it
    __syncthreads();
    if (!isA && w == 0 && lane < 16) {
        const float* pp = &partb[1][lane][0];
        f32x4 q0 = *(const f32x4*)pp;
        f32x4 q1 = *(const f32x4*)(pp + 4);
        f32x4 q2 = *(const f32x4*)(pp + 8);
        f32x4 q3 = *(const f32x4*)(pp + 12);
        f32x4 s4 = (q0 + q1) + (q2 + q3);
        *pOut = s4[0] + s4[1] + s4[2] + s4[3] + bd;
    }
}

extern "C" void kernel_launch(void* const* d_in, const int* in_sizes, int n_in,
                              void* d_out, int out_size, void* d_ws, size_t ws_size,
                              hipStream_t stream) {
    (void)in_sizes; (void)n_in; (void)d_ws; (void)ws_size; (void)out_size;
    const float* obss    = (const float*)d_in[0];
    const float* actions = (const float*)d_in[1];
    const float* W       = (const float*)d_in[2];
    const float* b       = (const float*)d_in[3];
    const float* Wdec    = (const float*)d_in[4];
    const float* bdec    = (const float*)d_in[5];
    float* out = (float*)d_out;
    lstm_fused<<<dim3(NSEQ / NB), dim3(512), 0, stream>>>(obss, actions, W, b, Wdec, bdec, out);
}